// Round 16
// baseline (89.791 us; speedup 1.0000x reference)
//
#include <hip/hip_runtime.h>
#include <math.h>

#define PI_F        3.14159265358979323846f
#define TWO_PI_F    6.2831853071795864769f
#define INV_TWO_PI_F 0.15915494309189533577f

typedef __attribute__((ext_vector_type(8))) short  bf16x8;
typedef __attribute__((ext_vector_type(8))) __bf16 bf16v8;
typedef __attribute__((ext_vector_type(4))) float  f32x4;

__device__ __forceinline__ bf16x8 cvt8(f32x4 a, f32x4 b) {
    bf16v8 v;
    v[0] = (__bf16)a.x; v[1] = (__bf16)a.y; v[2] = (__bf16)a.z; v[3] = (__bf16)a.w;
    v[4] = (__bf16)b.x; v[5] = (__bf16)b.y; v[6] = (__bf16)b.z; v[7] = (__bf16)b.w;
    return __builtin_bit_cast(bf16x8, v);
}

__device__ __forceinline__ unsigned pk2(float lo, float hi) {
    unsigned short l = __builtin_bit_cast(unsigned short, (__bf16)lo);
    unsigned short h = __builtin_bit_cast(unsigned short, (__bf16)hi);
    return ((unsigned)h << 16) | (unsigned)l;
}

// ------------------------------------------------------------------
// W prep (unchanged): wfb[level][(nt4*8+ks)*64 + lane] =
//   W[nt4*16+(l&15)][ks*32+(l>>4)*8 ..+8] as bf16x8 fragments.
// ------------------------------------------------------------------
__global__ __launch_bounds__(256) void wprep(
    const float* __restrict__ W0, const float* __restrict__ W1,
    const float* __restrict__ W2, __bf16* __restrict__ wfb)
{
    const int level = blockIdx.x >> 3;
    const int rem   = ((blockIdx.x & 7) << 8) | threadIdx.x;   // 0..2047
    const float* W  = level == 0 ? W0 : (level == 1 ? W1 : W2);
    const int l   = rem & 63;
    const int ks  = (rem >> 6) & 7;
    const int nt4 = rem >> 9;
    const int col = nt4 * 16 + (l & 15);
    const int k0  = ks * 32 + (l >> 4) * 8;
    const float* wp = W + col * 256 + k0;
    bf16x8 f = cvt8(*(const f32x4*)wp, *(const f32x4*)(wp + 4));
    *(bf16x8*)(wfb + (size_t)level * 16384 + (size_t)rem * 8) = f;
}

// ------------------------------------------------------------------
// Persistent depth-3 DMA-pipelined bf16-MFMA GEMM (unchanged from r15).
// ------------------------------------------------------------------
#define WAITN(NSTR) \
    asm volatile("s_waitcnt vmcnt(" NSTR ")" ::: "memory"); \
    __builtin_amdgcn_sched_barrier(0); \
    __builtin_amdgcn_s_barrier(); \
    __builtin_amdgcn_sched_barrier(0)

#define BAR2 \
    __builtin_amdgcn_sched_barrier(0); \
    __builtin_amdgcn_s_barrier(); \
    __builtin_amdgcn_sched_barrier(0)

#define ISSUE_SLAB(BUF, SLAB) \
    { _Pragma("unroll") \
      for (int q = 0; q < 4; ++q) { \
          const int r_ = w * 4 + q; \
          const float* src_ = x + (rowbase + (long)(SLAB) * 16 + r_) * 256 \
                                + ((lane ^ (r_ & 7)) << 2); \
          __builtin_amdgcn_global_load_lds( \
              (const __attribute__((address_space(1))) unsigned int*)src_, \
              (__attribute__((address_space(3))) unsigned int*) \
                  (lds + (BUF) * 4096 + r_ * 256), \
              16, 0, 0); \
      } }

#define COMPUTE(BUF) \
    { const float* base_ = lds + (BUF) * 4096 + l16 * 256; \
      _Pragma("unroll") \
      for (int ks = 0; ks < 8; ++ks) { \
          const int c0_ = ks * 8 + lq * 2; \
          f32x4 a0_ = *(const f32x4*)(base_ + (((c0_)     ^ sw) << 2)); \
          f32x4 a1_ = *(const f32x4*)(base_ + (((c0_ | 1) ^ sw) << 2)); \
          acc = __builtin_amdgcn_mfma_f32_16x16x32_bf16( \
                    wf[ks], cvt8(a0_, a1_), acc, 0, 0, 0); \
      } }

#define STOREY(SLAB) \
    { uint2 u_; u_.x = pk2(acc[0], acc[1]); u_.y = pk2(acc[2], acc[3]); \
      *(uint2*)(y + (rowbase + (long)(SLAB) * 16 + l16) * 64 + w * 16 + lq * 4) = u_; \
      acc = f32x4{0.f, 0.f, 0.f, 0.f}; }

__device__ __forceinline__ void gemm_body(
    long rowbase, float* lds,          // [3][16][256] f32
    const float* __restrict__ x, const __bf16* __restrict__ wfb,
    __bf16* __restrict__ y)
{
    constexpr int NS = 16;             // slabs per block
    const int tid  = threadIdx.x;
    const int lane = tid & 63;
    const int w    = tid >> 6;
    const int l16  = lane & 15;
    const int lq   = lane >> 4;
    const int sw   = l16 & 7;

    bf16x8 wf[8];
    {
        const __bf16* wb = wfb + (size_t)w * 4096 + (size_t)lane * 8;
        #pragma unroll
        for (int ks = 0; ks < 8; ++ks)
            wf[ks] = *(const bf16x8*)(wb + ks * 512);
    }
    asm volatile("" ::
        "v"(wf[0]), "v"(wf[1]), "v"(wf[2]), "v"(wf[3]),
        "v"(wf[4]), "v"(wf[5]), "v"(wf[6]), "v"(wf[7]));
    __builtin_amdgcn_sched_barrier(0);

    f32x4 acc = {0.f, 0.f, 0.f, 0.f};

    ISSUE_SLAB(0, 0)
    ISSUE_SLAB(1, 1)
    ISSUE_SLAB(2, 2)

    WAITN("8");  COMPUTE(0) BAR2; STOREY(0) ISSUE_SLAB(0, 3)
    WAITN("9");  COMPUTE(1) BAR2; STOREY(1) ISSUE_SLAB(1, 4)
    {
        int buf = 2;
        #pragma unroll 1
        for (int s = 2; s <= NS - 4; ++s) {
            WAITN("10"); COMPUTE(buf) BAR2; STOREY(s) ISSUE_SLAB(buf, s + 3)
            buf = (buf == 2) ? 0 : buf + 1;
        }
    }
    WAITN("10"); COMPUTE(1) BAR2; STOREY(NS - 3)
    WAITN("6");  COMPUTE(2) BAR2; STOREY(NS - 2)
    WAITN("2");  COMPUTE(0)       STOREY(NS - 1)
}

__global__ __launch_bounds__(256) void gemm_fused(
    const float* __restrict__ x0, const float* __restrict__ x1,
    const float* __restrict__ x2,
    const __bf16* __restrict__ wfb,
    __bf16* __restrict__ y0, __bf16* __restrict__ y1, __bf16* __restrict__ y2)
{
    __shared__ float lds[3 * 4096];    // 48 KB
    const int b = blockIdx.x;
    if (b < 512)       gemm_body((long)b * 256,         lds, x0, wfb,         y0);
    else if (b < 640)  gemm_body((long)(b - 512) * 256, lds, x1, wfb + 16384, y1);
    else               gemm_body((long)(b - 640) * 256, lds, x2, wfb + 32768, y2);
}

// ------------------------------------------------------------------
// Projection body. Weight phase unchanged (lane = point*8 + neighbor,
// 8-lane shuffle softmax -> wlds). PV phase RESTRUCTURED:
//   lane = h*32 + c: channels {2c,2c+1}, neighbors {4h..4h+3}.
//   4 u32 gathers per point (each instr covers TWO y-rows x 128B),
//   bf16 unpack by shift/mask, partial sums combined via shfl_xor(32),
//   lanes 0..31 store float2 (256B per point, fully coalesced).
// ------------------------------------------------------------------
template<int GS, int CG, int ROUNDS>
__device__ __forceinline__ void proj_body(
    int bid, float (*wlds)[128],
    const __bf16* __restrict__ y,      // [B*N][64] bf16
    const float* __restrict__ coords,  // [2][N]
    const int*   __restrict__ nh,      // [N][8]
    const float* __restrict__ oc,      // [2][B][N0]
    const float* __restrict__ sig_p,
    const float* __restrict__ kap_p,
    float* __restrict__ out,           // [B][N0][64]
    int N, int N0)
{
    constexpr int B = 2;
    static_assert(CG * GS == ROUNDS * 8, "slot layout");

    const int wslot = threadIdx.x >> 6;
    const int lane  = threadIdx.x & 63;
    const int wave  = (bid << 2) + wslot;
    const int gpb   = N / CG;
    const int b     = wave / gpb;
    const int g0    = (wave - b * gpb) * CG;

    const float sigma  = *sig_p;
    const float kappa  = *kap_p;
    const float inv2s2 = 1.0f / (2.0f * sigma * sigma);

    const int j  = lane & 7;
    const int pp = lane >> 3;

    #pragma unroll
    for (int r = 0; r < ROUNDS; ++r) {
        const int pidx = r * 8 + pp;
        const int q = pidx / GS;
        const int p = pidx - q * GS;
        const int g = g0 + q;
        const int idx = nh[g * 8 + j];
        const float clon = coords[idx];
        const float clat = coords[N + idx];
        const int n = g * GS + p;
        const float olon = oc[(long)b * N0 + n];
        const float olat = oc[(long)(B + b) * N0 + n];

        float dlon = olon - clon;
        float t = (dlon + PI_F) * INV_TWO_PI_F;   // floor-mod wrap to [-pi, pi)
        t -= floorf(t);
        dlon = t * TWO_PI_F - PI_F;
        const float dlat = olat - clat;

        float logw = -(dlat * dlat + dlon * dlon) * inv2s2
                   + kappa * (cosf(dlon) - 1.0f);

        float m = logw;
        m = fmaxf(m, __shfl_xor(m, 1));
        m = fmaxf(m, __shfl_xor(m, 2));
        m = fmaxf(m, __shfl_xor(m, 4));
        float e = expf(logw - m);
        float s = e;
        s += __shfl_xor(s, 1);
        s += __shfl_xor(s, 2);
        s += __shfl_xor(s, 4);
        wlds[wslot][r * 64 + lane] = e / s;
    }

    // no __syncthreads(): wlds[wslot] is same-wave data only.

    // ---- PV phase: lane = h*32 + c
    const int c  = lane & 31;          // channel pair: channels 2c, 2c+1
    const int h  = lane >> 5;          // neighbor half: j = 4h .. 4h+3
    const unsigned* yb2 = (const unsigned*)(y + (long)b * N * 64) + c;

    #pragma unroll
    for (int pidx = 0; pidx < CG * GS; ++pidx) {
        const int q = pidx / GS;
        const int p = pidx - q * GS;
        const int g = g0 + q;
        const int* nhg = nh + g * 8;
        const float* wrow = &wlds[wslot][(pidx >> 3) * 64 + (pidx & 7) * 8 + h * 4];
        float a0 = 0.0f, a1 = 0.0f;
        #pragma unroll
        for (int jj = 0; jj < 4; ++jj) {
            const unsigned v = yb2[(long)nhg[h * 4 + jj] * 32];
            const float lo = __builtin_bit_cast(float, v << 16);
            const float hi = __builtin_bit_cast(float, v & 0xFFFF0000u);
            const float wv = wrow[jj];
            a0 = fmaf(wv, lo, a0);
            a1 = fmaf(wv, hi, a1);
        }
        a0 += __shfl_xor(a0, 32);
        a1 += __shfl_xor(a1, 32);
        if (lane < 32) {
            const int n = g * GS + p;
            *(float2*)(out + ((long)b * N0 + n) * 64 + 2 * c) =
                make_float2(a0, a1);
        }
    }
}

// Fused projection: blocks [0,4096) L0, [4096,8192) L1, [8192,10240) L2.
__global__ __launch_bounds__(256) void proj_fused(
    const __bf16* __restrict__ y0, const __bf16* __restrict__ y1,
    const __bf16* __restrict__ y2,
    const float* __restrict__ c0, const float* __restrict__ c1,
    const float* __restrict__ c2,
    const int* __restrict__ nh0, const int* __restrict__ nh1,
    const int* __restrict__ nh2,
    const float* __restrict__ oc,
    const float* __restrict__ sig0, const float* __restrict__ sig1,
    const float* __restrict__ sig2,
    const float* __restrict__ kap0, const float* __restrict__ kap1,
    const float* __restrict__ kap2,
    float* __restrict__ out)
{
    __shared__ float wlds[4][128];
    const size_t SLICE = (size_t)2 * 65536 * 64;
    const int b = blockIdx.x;
    if (b < 4096)
        proj_body<1, 8, 1>(b, wlds, y0, c0, nh0, oc, sig0, kap0,
                           out, 65536, 65536);
    else if (b < 8192)
        proj_body<4, 2, 1>(b - 4096, wlds, y1, c1, nh1, oc, sig1, kap1,
                           out + SLICE, 16384, 65536);
    else
        proj_body<16, 1, 2>(b - 8192, wlds, y2, c2, nh2, oc, sig2, kap2,
                            out + 2 * SLICE, 4096, 65536);
}

// ------------------------------------------------------------------
extern "C" void kernel_launch(void* const* d_in, const int* in_sizes, int n_in,
                              void* d_out, int out_size, void* d_ws, size_t ws_size,
                              hipStream_t stream)
{
    const float* x0   = (const float*)d_in[0];
    const float* x1   = (const float*)d_in[1];
    const float* x2   = (const float*)d_in[2];
    const float* W0   = (const float*)d_in[3];
    const float* W1   = (const float*)d_in[4];
    const float* W2   = (const float*)d_in[5];
    const float* sig0 = (const float*)d_in[6];
    const float* sig1 = (const float*)d_in[7];
    const float* sig2 = (const float*)d_in[8];
    const float* kap0 = (const float*)d_in[9];
    const float* kap1 = (const float*)d_in[10];
    const float* kap2 = (const float*)d_in[11];
    const float* c0   = (const float*)d_in[12];
    const float* c1   = (const float*)d_in[13];
    const float* c2   = (const float*)d_in[14];
    const int*   nh0  = (const int*)d_in[15];
    const int*   nh1  = (const int*)d_in[16];
    const int*   nh2  = (const int*)d_in[17];
    const float* oc   = (const float*)d_in[18];

    float* out = (float*)d_out;
    // d_ws layout (bf16 elements): wfb[3*16384] | y0 | y1 | y2
    __bf16* wfb = (__bf16*)d_ws;
    __bf16* y0  = wfb + 3 * 16384;
    __bf16* y1  = y0 + (size_t)2 * 65536 * 64;
    __bf16* y2  = y1 + (size_t)2 * 16384 * 64;

    wprep<<<24, 256, 0, stream>>>(W0, W1, W2, wfb);
    gemm_fused<<<672, 256, 0, stream>>>(x0, x1, x2, wfb, y0, y1, y2);
    proj_fused<<<10240, 256, 0, stream>>>(y0, y1, y2, c0, c1, c2,
                                          nh0, nh1, nh2, oc,
                                          sig0, sig1, sig2,
                                          kap0, kap1, kap2, out);
}

// Round 17
// 87.899 us; speedup vs baseline: 1.0215x; 1.0215x over previous
//
#include <hip/hip_runtime.h>
#include <math.h>

#define PI_F        3.14159265358979323846f
#define TWO_PI_F    6.2831853071795864769f
#define INV_TWO_PI_F 0.15915494309189533577f

typedef __attribute__((ext_vector_type(8))) short  bf16x8;
typedef __attribute__((ext_vector_type(8))) __bf16 bf16v8;
typedef __attribute__((ext_vector_type(4))) float  f32x4;

__device__ __forceinline__ bf16x8 cvt8(f32x4 a, f32x4 b) {
    bf16v8 v;
    v[0] = (__bf16)a.x; v[1] = (__bf16)a.y; v[2] = (__bf16)a.z; v[3] = (__bf16)a.w;
    v[4] = (__bf16)b.x; v[5] = (__bf16)b.y; v[6] = (__bf16)b.z; v[7] = (__bf16)b.w;
    return __builtin_bit_cast(bf16x8, v);
}

__device__ __forceinline__ unsigned pk2(float lo, float hi) {
    unsigned short l = __builtin_bit_cast(unsigned short, (__bf16)lo);
    unsigned short h = __builtin_bit_cast(unsigned short, (__bf16)hi);
    return ((unsigned)h << 16) | (unsigned)l;
}

// ------------------------------------------------------------------
// W prep: wfb[level][(nt4*8+ks)*64 + lane] =
//   W[nt4*16+(l&15)][ks*32+(l>>4)*8 ..+8] as bf16x8 fragments.
// ------------------------------------------------------------------
__global__ __launch_bounds__(256) void wprep(
    const float* __restrict__ W0, const float* __restrict__ W1,
    const float* __restrict__ W2, __bf16* __restrict__ wfb)
{
    const int level = blockIdx.x >> 3;
    const int rem   = ((blockIdx.x & 7) << 8) | threadIdx.x;   // 0..2047
    const float* W  = level == 0 ? W0 : (level == 1 ? W1 : W2);
    const int l   = rem & 63;
    const int ks  = (rem >> 6) & 7;
    const int nt4 = rem >> 9;
    const int col = nt4 * 16 + (l & 15);
    const int k0  = ks * 32 + (l >> 4) * 8;
    const float* wp = W + col * 256 + k0;
    bf16x8 f = cvt8(*(const f32x4*)wp, *(const f32x4*)(wp + 4));
    *(bf16x8*)(wfb + (size_t)level * 16384 + (size_t)rem * 8) = f;
}

// ------------------------------------------------------------------
// Persistent depth-3 DMA-pipelined bf16-MFMA GEMM (round-15 form,
// best measured): y = x (.) W^T, K=256, Do=64, y bf16.
// Block = 4 waves, 16 consecutive 16-row slabs. LDS = 3 x 16KB
// buffers (48KB -> 3 blocks/CU; grid 672 fully co-resident).
// Counted vmcnt keeps 2 future slabs' DMAs in flight across raw
// s_barriers (no vmcnt(0) drain in the loop).
// ------------------------------------------------------------------
#define WAITN(NSTR) \
    asm volatile("s_waitcnt vmcnt(" NSTR ")" ::: "memory"); \
    __builtin_amdgcn_sched_barrier(0); \
    __builtin_amdgcn_s_barrier(); \
    __builtin_amdgcn_sched_barrier(0)

#define BAR2 \
    __builtin_amdgcn_sched_barrier(0); \
    __builtin_amdgcn_s_barrier(); \
    __builtin_amdgcn_sched_barrier(0)

#define ISSUE_SLAB(BUF, SLAB) \
    { _Pragma("unroll") \
      for (int q = 0; q < 4; ++q) { \
          const int r_ = w * 4 + q; \
          const float* src_ = x + (rowbase + (long)(SLAB) * 16 + r_) * 256 \
                                + ((lane ^ (r_ & 7)) << 2); \
          __builtin_amdgcn_global_load_lds( \
              (const __attribute__((address_space(1))) unsigned int*)src_, \
              (__attribute__((address_space(3))) unsigned int*) \
                  (lds + (BUF) * 4096 + r_ * 256), \
              16, 0, 0); \
      } }

#define COMPUTE(BUF) \
    { const float* base_ = lds + (BUF) * 4096 + l16 * 256; \
      _Pragma("unroll") \
      for (int ks = 0; ks < 8; ++ks) { \
          const int c0_ = ks * 8 + lq * 2; \
          f32x4 a0_ = *(const f32x4*)(base_ + (((c0_)     ^ sw) << 2)); \
          f32x4 a1_ = *(const f32x4*)(base_ + (((c0_ | 1) ^ sw) << 2)); \
          acc = __builtin_amdgcn_mfma_f32_16x16x32_bf16( \
                    wf[ks], cvt8(a0_, a1_), acc, 0, 0, 0); \
      } }

#define STOREY(SLAB) \
    { uint2 u_; u_.x = pk2(acc[0], acc[1]); u_.y = pk2(acc[2], acc[3]); \
      *(uint2*)(y + (rowbase + (long)(SLAB) * 16 + l16) * 64 + w * 16 + lq * 4) = u_; \
      acc = f32x4{0.f, 0.f, 0.f, 0.f}; }

__device__ __forceinline__ void gemm_body(
    long rowbase, float* lds,          // [3][16][256] f32
    const float* __restrict__ x, const __bf16* __restrict__ wfb,
    __bf16* __restrict__ y)
{
    constexpr int NS = 16;             // slabs per block
    const int tid  = threadIdx.x;
    const int lane = tid & 63;
    const int w    = tid >> 6;
    const int l16  = lane & 15;
    const int lq   = lane >> 4;
    const int sw   = l16 & 7;

    bf16x8 wf[8];
    {
        const __bf16* wb = wfb + (size_t)w * 4096 + (size_t)lane * 8;
        #pragma unroll
        for (int ks = 0; ks < 8; ++ks)
            wf[ks] = *(const bf16x8*)(wb + ks * 512);
    }
    asm volatile("" ::
        "v"(wf[0]), "v"(wf[1]), "v"(wf[2]), "v"(wf[3]),
        "v"(wf[4]), "v"(wf[5]), "v"(wf[6]), "v"(wf[7]));
    __builtin_amdgcn_sched_barrier(0);

    f32x4 acc = {0.f, 0.f, 0.f, 0.f};

    ISSUE_SLAB(0, 0)
    ISSUE_SLAB(1, 1)
    ISSUE_SLAB(2, 2)

    WAITN("8");  COMPUTE(0) BAR2; STOREY(0) ISSUE_SLAB(0, 3)
    WAITN("9");  COMPUTE(1) BAR2; STOREY(1) ISSUE_SLAB(1, 4)
    {
        int buf = 2;
        #pragma unroll 1
        for (int s = 2; s <= NS - 4; ++s) {
            WAITN("10"); COMPUTE(buf) BAR2; STOREY(s) ISSUE_SLAB(buf, s + 3)
            buf = (buf == 2) ? 0 : buf + 1;
        }
    }
    WAITN("10"); COMPUTE(1) BAR2; STOREY(NS - 3)
    WAITN("6");  COMPUTE(2) BAR2; STOREY(NS - 2)
    WAITN("2");  COMPUTE(0)       STOREY(NS - 1)
}

__global__ __launch_bounds__(256) void gemm_fused(
    const float* __restrict__ x0, const float* __restrict__ x1,
    const float* __restrict__ x2,
    const __bf16* __restrict__ wfb,
    __bf16* __restrict__ y0, __bf16* __restrict__ y1, __bf16* __restrict__ y2)
{
    __shared__ float lds[3 * 4096];    // 48 KB
    const int b = blockIdx.x;
    if (b < 512)       gemm_body((long)b * 256,         lds, x0, wfb,         y0);
    else if (b < 640)  gemm_body((long)(b - 512) * 256, lds, x1, wfb + 16384, y1);
    else               gemm_body((long)(b - 640) * 256, lds, x2, wfb + 32768, y2);
}

// ------------------------------------------------------------------
// Projection body (round-15 form, best measured): weight phase with
// 8-lane shuffle softmax -> per-wave LDS; PV phase lane = channel,
// 8 coalesced 128B row-gathers per point, full-wave 256B stores.
// wlds is per-wave -> no block barrier.
// ------------------------------------------------------------------
template<int GS, int CG, int ROUNDS>
__device__ __forceinline__ void proj_body(
    int bid, float (*wlds)[128],
    const __bf16* __restrict__ y,      // [B*N][64] bf16
    const float* __restrict__ coords,  // [2][N]
    const int*   __restrict__ nh,      // [N][8]
    const float* __restrict__ oc,      // [2][B][N0]
    const float* __restrict__ sig_p,
    const float* __restrict__ kap_p,
    float* __restrict__ out,           // [B][N0][64]
    int N, int N0)
{
    constexpr int B = 2;
    static_assert(CG * GS == ROUNDS * 8, "slot layout");

    const int wslot = threadIdx.x >> 6;
    const int lane  = threadIdx.x & 63;
    const int wave  = (bid << 2) + wslot;
    const int gpb   = N / CG;
    const int b     = wave / gpb;
    const int g0    = (wave - b * gpb) * CG;

    const float sigma  = *sig_p;
    const float kappa  = *kap_p;
    const float inv2s2 = 1.0f / (2.0f * sigma * sigma);

    const int j  = lane & 7;
    const int pp = lane >> 3;

    #pragma unroll
    for (int r = 0; r < ROUNDS; ++r) {
        const int pidx = r * 8 + pp;
        const int q = pidx / GS;
        const int p = pidx - q * GS;
        const int g = g0 + q;
        const int idx = nh[g * 8 + j];
        const float clon = coords[idx];
        const float clat = coords[N + idx];
        const int n = g * GS + p;
        const float olon = oc[(long)b * N0 + n];
        const float olat = oc[(long)(B + b) * N0 + n];

        float dlon = olon - clon;
        float t = (dlon + PI_F) * INV_TWO_PI_F;   // floor-mod wrap to [-pi, pi)
        t -= floorf(t);
        dlon = t * TWO_PI_F - PI_F;
        const float dlat = olat - clat;

        float logw = -(dlat * dlat + dlon * dlon) * inv2s2
                   + kappa * (cosf(dlon) - 1.0f);

        float m = logw;
        m = fmaxf(m, __shfl_xor(m, 1));
        m = fmaxf(m, __shfl_xor(m, 2));
        m = fmaxf(m, __shfl_xor(m, 4));
        float e = expf(logw - m);
        float s = e;
        s += __shfl_xor(s, 1);
        s += __shfl_xor(s, 2);
        s += __shfl_xor(s, 4);
        wlds[wslot][r * 64 + lane] = e / s;
    }

    // no __syncthreads(): wlds[wslot] is same-wave data only.

    const int d = lane;
    const __bf16* yb = y + (long)b * N * 64 + d;
    #pragma unroll
    for (int pidx = 0; pidx < CG * GS; ++pidx) {
        const int q = pidx / GS;
        const int p = pidx - q * GS;
        const int g = g0 + q;
        const int* nhg = nh + g * 8;
        const float* wrow = &wlds[wslot][(pidx >> 3) * 64 + (pidx & 7) * 8];
        float a = 0.0f;
        #pragma unroll
        for (int jj = 0; jj < 8; ++jj)
            a = fmaf(wrow[jj], (float)yb[(long)nhg[jj] * 64], a);
        const int n = g * GS + p;
        out[((long)b * N0 + n) * 64 + d] = a;
    }
}

// Fused projection: blocks [0,4096) L0, [4096,8192) L1, [8192,10240) L2.
__global__ __launch_bounds__(256) void proj_fused(
    const __bf16* __restrict__ y0, const __bf16* __restrict__ y1,
    const __bf16* __restrict__ y2,
    const float* __restrict__ c0, const float* __restrict__ c1,
    const float* __restrict__ c2,
    const int* __restrict__ nh0, const int* __restrict__ nh1,
    const int* __restrict__ nh2,
    const float* __restrict__ oc,
    const float* __restrict__ sig0, const float* __restrict__ sig1,
    const float* __restrict__ sig2,
    const float* __restrict__ kap0, const float* __restrict__ kap1,
    const float* __restrict__ kap2,
    float* __restrict__ out)
{
    __shared__ float wlds[4][128];
    const size_t SLICE = (size_t)2 * 65536 * 64;
    const int b = blockIdx.x;
    if (b < 4096)
        proj_body<1, 8, 1>(b, wlds, y0, c0, nh0, oc, sig0, kap0,
                           out, 65536, 65536);
    else if (b < 8192)
        proj_body<4, 2, 1>(b - 4096, wlds, y1, c1, nh1, oc, sig1, kap1,
                           out + SLICE, 16384, 65536);
    else
        proj_body<16, 1, 2>(b - 8192, wlds, y2, c2, nh2, oc, sig2, kap2,
                            out + 2 * SLICE, 4096, 65536);
}

// ------------------------------------------------------------------
extern "C" void kernel_launch(void* const* d_in, const int* in_sizes, int n_in,
                              void* d_out, int out_size, void* d_ws, size_t ws_size,
                              hipStream_t stream)
{
    const float* x0   = (const float*)d_in[0];
    const float* x1   = (const float*)d_in[1];
    const float* x2   = (const float*)d_in[2];
    const float* W0   = (const float*)d_in[3];
    const float* W1   = (const float*)d_in[4];
    const float* W2   = (const float*)d_in[5];
    const float* sig0 = (const float*)d_in[6];
    const float* sig1 = (const float*)d_in[7];
    const float* sig2 = (const float*)d_in[8];
    const float* kap0 = (const float*)d_in[9];
    const float* kap1 = (const float*)d_in[10];
    const float* kap2 = (const float*)d_in[11];
    const float* c0   = (const float*)d_in[12];
    const float* c1   = (const float*)d_in[13];
    const float* c2   = (const float*)d_in[14];
    const int*   nh0  = (const int*)d_in[15];
    const int*   nh1  = (const int*)d_in[16];
    const int*   nh2  = (const int*)d_in[17];
    const float* oc   = (const float*)d_in[18];

    float* out = (float*)d_out;
    // d_ws layout (bf16 elements): wfb[3*16384] | y0 | y1 | y2
    __bf16* wfb = (__bf16*)d_ws;
    __bf16* y0  = wfb + 3 * 16384;
    __bf16* y1  = y0 + (size_t)2 * 65536 * 64;
    __bf16* y2  = y1 + (size_t)2 * 16384 * 64;

    wprep<<<24, 256, 0, stream>>>(W0, W1, W2, wfb);
    gemm_fused<<<672, 256, 0, stream>>>(x0, x1, x2, wfb, y0, y1, y2);
    proj_fused<<<10240, 256, 0, stream>>>(y0, y1, y2, c0, c1, c2,
                                          nh0, nh1, nh2, oc,
                                          sig0, sig1, sig2,
                                          kap0, kap1, kap2, out);
}